// Round 9
// baseline (973.697 us; speedup 1.0000x reference)
//
#include <hip/hip_runtime.h>
#include <hip/hip_bf16.h>
#include <hip/hip_cooperative_groups.h>

namespace cg = cooperative_groups;

// ---------------------------------------------------------------------------
// ramsey_NN: node MLP (3 layers, train-mode BN) + all-pairs edge head.
// N=2048, F=64, H=128, C=2.  E = N(N-1)/2 = 2096128.
//
// R9 vs R8 (R8: edge kernels fixed via launch_bounds; the ~110 us node chain
// is now the biggest chunk):
//   * k_node: ONE cooperative kernel (256 blocks, 1/CU) replacing
//     k_l1/k_l2/k_l3/k_bi. Activations live in LDS (block owns its 8 nodes);
//     BN stats via global atomics + grid.sync(); stats read back with
//     agent-scope atomic loads (per-XCD L2 non-coherence); W5 frag-physical
//     conversion + T-build fused in.
//   * edge_p1: launch_bounds(256,8) — VGPR already 64, allow 8 waves/SIMD.
//   * edge_p2: launch_bounds(256,6).
// ---------------------------------------------------------------------------

typedef short short8 __attribute__((ext_vector_type(8)));   // 8 x bf16
typedef float floatx4 __attribute__((ext_vector_type(4)));  // MFMA C/D
typedef float float2v __attribute__((ext_vector_type(2)));  // packed f32 pair

#define NN 2048
#define EPSV 1e-5f
#define EDGEF 2096128.f

__device__ __forceinline__ float bf2f(short s) {
    return __uint_as_float(((unsigned)(unsigned short)s) << 16);
}
__device__ __forceinline__ short f2bf(float f) {   // RNE
    unsigned u = __float_as_uint(f);
    unsigned r = (u + 0x7FFFu + ((u >> 16) & 1u)) >> 16;
    return (short)r;
}
__device__ __forceinline__ float lrelu(float x) { return fmaxf(x, 0.01f * x); }
__device__ __forceinline__ float2v lrelu2(float2v z) {
    float2v r; r.x = fmaxf(z.x, 0.01f * z.x); r.y = fmaxf(z.y, 0.01f * z.y);
    return r;
}
__device__ __forceinline__ float2v fma2(float2v a, float2v b, float2v c) {
    float2v r; r.x = fmaf(a.x, b.x, c.x); r.y = fmaf(a.y, b.y, c.y); return r;
}
__device__ __forceinline__ float aload(const float* p) {   // device-coherent load
    return __hip_atomic_load(p, __ATOMIC_RELAXED, __HIP_MEMORY_SCOPE_AGENT);
}

// fragment-physical chunk index (16x16x32 bf16, A/B identity layout)
__device__ __forceinline__ int physB(int h, int f) {
    return ((((h >> 4) * 2 + (f >> 5)) * 64 + ((f >> 3) & 3) * 16 + (h & 15)) * 8) + (f & 7);
}

// 1-D active-tile decode: rows-of-8 nodes, j-tiles of 64.
// Row ig8 pinned to XCD ig8%8 (blockIdx%8 round-robin heuristic).
// Per-XCD slots: sum_{m=0}^{31}(32-m)=528; grid = 4224.
__device__ __forceinline__ void decode_tile(int bid, int& i0, int& j0, bool& str) {
    int s = bid >> 3, m = 0;
#pragma unroll 1
    while (s >= 32 - m) { s -= 32 - m; ++m; }
    i0 = ((bid & 7) + (m << 3)) * 8;
    j0 = (m + s) * 64;
    str = (s == 0);
}

// ---------------- fused node pipeline (cooperative, 256 blocks x 8 nodes) ----
__global__ __launch_bounds__(256) void k_node(
    const float* __restrict__ nf,
    const float* __restrict__ W1, const float* __restrict__ b1,
    const float* __restrict__ g1, const float* __restrict__ be1,
    const float* __restrict__ W2, const float* __restrict__ b2,
    const float* __restrict__ g2, const float* __restrict__ be2,
    const float* __restrict__ W3, const float* __restrict__ b3,
    const float* __restrict__ W5,
    float* __restrict__ stat1, float* __restrict__ stat2,
    short* __restrict__ hb, short* __restrict__ T)
{
    cg::grid_group grid = cg::this_grid();

    __shared__ float xl[8 * 64];      // nf rows (kept for residual)
    __shared__ float sA1[8 * 128];    // act1
    __shared__ float sA2[8 * 128];    // act2
    __shared__ short sW5[8192];       // W5 bf16 frag-physical
    __shared__ short sH[8 * 64];      // hb rows
    __shared__ float sS[128], sQ[128];
    __shared__ float nA[128], nB[128];

    int t = threadIdx.x, n0 = blockIdx.x * 8;

    // stage: W5 -> frag-physical bf16 (per block), nf rows, zero stats
    for (int k = 0; k < 32; ++k) {
        int idx = t + 256 * k;                 // f*128+h
        sW5[physB(idx & 127, idx >> 7)] = f2bf(W5[idx]);
    }
    xl[t] = nf[(size_t)n0 * 64 + t];
    xl[t + 256] = nf[(size_t)n0 * 64 + t + 256];
    if (t < 128) { sS[t] = 0.f; sQ[t] = 0.f; }
    __syncthreads();

    int nl = t >> 5, h0 = (t & 31) * 4;

    // ---- layer 1 ----
    {
        float acc[4];
        for (int k = 0; k < 4; ++k) acc[k] = b1[h0 + k];
        for (int f = 0; f < 64; ++f) {
            float r = xl[nl * 64 + f];
            const float* wr = W1 + f * 128 + h0;
            for (int k = 0; k < 4; ++k) acc[k] = fmaf(r, wr[k], acc[k]);
        }
        for (int k = 0; k < 4; ++k) {
            float a = lrelu(acc[k]);
            sA1[nl * 128 + h0 + k] = a;
            atomicAdd(&sS[h0 + k], a);
            atomicAdd(&sQ[h0 + k], a * a);
        }
    }
    __syncthreads();
    if (t < 128) atomicAdd(&stat1[t], sS[t]);
    else atomicAdd(&stat1[128 + (t - 128)], sQ[t - 128]);
    grid.sync();

    // ---- BN1 fold + zero stats for layer 2 ----
    if (t < 128) {
        float s = aload(stat1 + t);
        float q = aload(stat1 + 128 + t);
        float m = s * (1.f / 2048.f);
        float v = q * (1.f / 2048.f) - m * m;
        float sc = rsqrtf(v + EPSV) * g1[t];
        nA[t] = sc;
        nB[t] = be1[t] - m * sc;
        sS[t] = 0.f; sQ[t] = 0.f;
    }
    __syncthreads();
    for (int k = 0; k < 4; ++k) {
        int e = t + 256 * k;
        int h = e & 127;
        sA1[e] = sA1[e] * nA[h] + nB[h];
    }
    __syncthreads();

    // ---- layer 2 ----
    {
        float acc[4];
        for (int k = 0; k < 4; ++k) acc[k] = b2[h0 + k];
        for (int hi = 0; hi < 128; ++hi) {
            float r = sA1[nl * 128 + hi];
            const float* wr = W2 + hi * 128 + h0;
            for (int k = 0; k < 4; ++k) acc[k] = fmaf(r, wr[k], acc[k]);
        }
        for (int k = 0; k < 4; ++k) {
            float a = lrelu(acc[k]);
            sA2[nl * 128 + h0 + k] = a;
            atomicAdd(&sS[h0 + k], a);
            atomicAdd(&sQ[h0 + k], a * a);
        }
    }
    __syncthreads();
    if (t < 128) atomicAdd(&stat2[t], sS[t]);
    else atomicAdd(&stat2[128 + (t - 128)], sQ[t - 128]);
    grid.sync();

    // ---- BN2 fold ----
    if (t < 128) {
        float s = aload(stat2 + t);
        float q = aload(stat2 + 128 + t);
        float m = s * (1.f / 2048.f);
        float v = q * (1.f / 2048.f) - m * m;
        float sc = rsqrtf(v + EPSV) * g2[t];
        nA[t] = sc;
        nB[t] = be2[t] - m * sc;
    }
    __syncthreads();
    for (int k = 0; k < 4; ++k) {
        int e = t + 256 * k;
        int h = e & 127;
        sA2[e] = sA2[e] * nA[h] + nB[h];
    }
    __syncthreads();

    // ---- layer 3 + residual -> sH + hb ----
    {
        int f0 = (t & 31) * 2;
        float acc0 = 0.f, acc1 = 0.f;
        for (int hi = 0; hi < 128; ++hi) {
            float r = sA2[nl * 128 + hi];
            const float* wr = W3 + hi * 64 + f0;
            acc0 = fmaf(r, wr[0], acc0);
            acc1 = fmaf(r, wr[1], acc1);
        }
        float v0 = acc0 + b3[f0] + xl[nl * 64 + f0];
        float v1 = acc1 + b3[f0 + 1] + xl[nl * 64 + f0 + 1];
        short s0 = f2bf(v0), s1 = f2bf(v1);
        sH[nl * 64 + f0] = s0;
        sH[nl * 64 + f0 + 1] = s1;
        unsigned p = (unsigned)(unsigned short)s0 | ((unsigned)(unsigned short)s1 << 16);
        ((unsigned*)hb)[(size_t)(n0 + nl) * 32 + (f0 >> 1)] = p;
    }
    __syncthreads();

    // ---- T build: T[i] = diag(h_i) @ W5 ----
    for (int i = 0; i < 8; ++i) {
        short8* dst = (short8*)(T + (size_t)(n0 + i) * 8192);
#pragma unroll
        for (int k = 0; k < 4; ++k) {
            int c = t + 256 * k;                 // chunk 0..1023
            int ks = (c >> 6) & 1, quad = (c & 63) >> 4;
            int fb = ks * 32 + quad * 8;
            short8 wv = ((const short8*)sW5)[c];
            short8 hv = *(const short8*)(sH + i * 64 + fb);
            short8 ov;
#pragma unroll
            for (int e = 0; e < 8; ++e) ov[e] = f2bf(bf2f(wv[e]) * bf2f(hv[e]));
            dst[c] = ov;
        }
    }
}

// ---------------- BN+softmax fold (1 block) ----------------------------------
__global__ void k_mid(const float* __restrict__ SQe8, const float* __restrict__ W6,
                      const float* __restrict__ b6, const float* __restrict__ g5,
                      const float* __restrict__ be5, float* __restrict__ w6d,
                      float* __restrict__ b6d) {
    __shared__ float part[128];
    int h = threadIdx.x;
    float s = 0.f, q = 0.f;
    for (int x = 0; x < 8; ++x) {
        s += SQe8[x * 256 + h];
        q += SQe8[x * 256 + 128 + h];
    }
    float m = s / EDGEF;
    float v = q / EDGEF - m * m;
    float sc = rsqrtf(v + EPSV);
    float dW = W6[h * 2] - W6[h * 2 + 1];
    float sg = sc * g5[h];
    w6d[h] = sg * dW;
    part[h] = (be5[h] - m * sg) * dW;
    __syncthreads();
    if (h == 0) {
        float acc = b6[0] - b6[1];
        for (int k = 0; k < 128; ++k) acc += part[k];
        b6d[0] = acc;
    }
}

// ---------------- edge pass 1: BN stats --------------------------------------
// (256,8): VGPR already at 64 under (256,4) — same codegen, 2x residency cap.
__global__ __launch_bounds__(256, 8) void edge_p1(
    const short* __restrict__ hb, const short* __restrict__ T,
    const float* __restrict__ b5, float* __restrict__ SQe8)
{
    int i0, j0; bool str;
    decode_tile(blockIdx.x, i0, j0, str);

    int t = threadIdx.x, lane = t & 63, w = t >> 6;
    int quad = lane >> 4, col = lane & 15;

    short8 hfr[4][2];
#pragma unroll
    for (int mt = 0; mt < 4; ++mt)
#pragma unroll
        for (int ks = 0; ks < 2; ++ks)
            hfr[mt][ks] = *(const short8*)(hb + (size_t)(j0 + mt * 16 + col) * 64 + ks * 32 + quad * 8);

    const short* Tb = T + (size_t)i0 * 8192;
    int toff[2][2];
#pragma unroll
    for (int n = 0; n < 2; ++n)
#pragma unroll
        for (int ks = 0; ks < 2; ++ks)
            toff[n][ks] = ((((w * 2 + n) * 2 + ks) * 64) + lane) * 8;

    float b5c[2] = { b5[w * 32 + col], b5[w * 32 + 16 + col] };
    float2v S2[2], Q2[2];
#pragma unroll
    for (int n = 0; n < 2; ++n) { S2[n] = 0.f; Q2[n] = 0.f; }

    short8 ta[2][2], tb[2][2];

    auto prefetch = [&](short8 (&dst)[2][2], int i) {
        const short* Tn = Tb + (size_t)i * 8192;
#pragma unroll
        for (int n = 0; n < 2; ++n)
#pragma unroll
            for (int ks = 0; ks < 2; ++ks)
                dst[n][ks] = *(const short8*)(Tn + toff[n][ks]);
    };

    // clean body: no triangle masking (4160 of 4224 blocks)
    auto bodyC = [&](short8 (&tc)[2][2]) {
#pragma unroll
        for (int n = 0; n < 2; ++n) {
#pragma unroll
            for (int mt = 0; mt < 4; ++mt) {
                floatx4 c = {b5c[n], b5c[n], b5c[n], b5c[n]};
                c = __builtin_amdgcn_mfma_f32_16x16x32_bf16(hfr[mt][0], tc[n][0], c, 0, 0, 0);
                c = __builtin_amdgcn_mfma_f32_16x16x32_bf16(hfr[mt][1], tc[n][1], c, 0, 0, 0);
                float2v z01, z23;
                z01.x = c[0]; z01.y = c[1];
                z23.x = c[2]; z23.y = c[3];
                float2v a01 = lrelu2(z01), a23 = lrelu2(z23);
                S2[n] += a01 + a23;
                Q2[n] = fma2(a01, a01, Q2[n]);
                Q2[n] = fma2(a23, a23, Q2[n]);
            }
        }
    };

    // masked body: diagonal-straddling blocks only (64 of 4224)
    auto bodyM = [&](int i, short8 (&tc)[2][2]) {
        int igi = i0 + i;
#pragma unroll
        for (int n = 0; n < 2; ++n) {
#pragma unroll
            for (int mt = 0; mt < 4; ++mt) {
                floatx4 c = {b5c[n], b5c[n], b5c[n], b5c[n]};
                c = __builtin_amdgcn_mfma_f32_16x16x32_bf16(hfr[mt][0], tc[n][0], c, 0, 0, 0);
                c = __builtin_amdgcn_mfma_f32_16x16x32_bf16(hfr[mt][1], tc[n][1], c, 0, 0, 0);
                int jb = j0 + mt * 16 + quad * 4;
                float2v z01, z23;
                z01.x = (jb + 0 > igi) ? c[0] : 0.f;
                z01.y = (jb + 1 > igi) ? c[1] : 0.f;
                z23.x = (jb + 2 > igi) ? c[2] : 0.f;
                z23.y = (jb + 3 > igi) ? c[3] : 0.f;
                float2v a01 = lrelu2(z01), a23 = lrelu2(z23);
                S2[n] += a01 + a23;
                Q2[n] = fma2(a01, a01, Q2[n]);
                Q2[n] = fma2(a23, a23, Q2[n]);
            }
        }
    };

    prefetch(ta, 0);
    if (!str) {
        for (int ii = 0; ii < 8; ii += 2) {
            prefetch(tb, ii + 1);
            bodyC(ta);
            if (ii + 2 < 8) prefetch(ta, ii + 2);
            bodyC(tb);
        }
    } else {
        for (int ii = 0; ii < 8; ii += 2) {
            prefetch(tb, ii + 1);
            bodyM(ii, ta);
            if (ii + 2 < 8) prefetch(ta, ii + 2);
            bodyM(ii + 1, tb);
        }
    }

    float* dst = SQe8 + (blockIdx.x & 7) * 256;
#pragma unroll
    for (int n = 0; n < 2; ++n) {
        float Sa = S2[n].x + S2[n].y;
        float Qa = Q2[n].x + Q2[n].y;
        Sa += __shfl_xor(Sa, 16); Sa += __shfl_xor(Sa, 32);
        Qa += __shfl_xor(Qa, 16); Qa += __shfl_xor(Qa, 32);
        if (quad == 0) {
            atomicAdd(&dst[w * 32 + n * 16 + col], Sa);
            atomicAdd(&dst[128 + w * 32 + n * 16 + col], Qa);
        }
    }
}

// ---------------- edge pass 2: probabilities + symmetric write ---------------
__global__ __launch_bounds__(256, 6) void edge_p2(
    const short* __restrict__ hb, const short* __restrict__ T,
    const float* __restrict__ b5, const float* __restrict__ w6d,
    const float* __restrict__ b6dp, float* __restrict__ out)
{
    int i0, j0; bool str;
    decode_tile(blockIdx.x, i0, j0, str);
    __shared__ float sV[4][8][64];    // per-wave partial h-sums (8 KB)
    __shared__ float sP[8][65];       // probs, padded (mirror transpose)

    int t = threadIdx.x, lane = t & 63, w = t >> 6;
    int quad = lane >> 4, col = lane & 15;

    float bb = b6dp[0];
    float b5q[2][4];
    float2v wq[2][2];                 // w6d at (m, r01/r23)
#pragma unroll
    for (int m = 0; m < 2; ++m)
#pragma unroll
        for (int r = 0; r < 4; ++r) {
            int h = w * 32 + m * 16 + quad * 4 + r;
            b5q[m][r] = b5[h];
            ((float*)&wq[m][r >> 1])[r & 1] = w6d[h];
        }

    short8 hfr[4][2];
#pragma unroll
    for (int mt = 0; mt < 4; ++mt)
#pragma unroll
        for (int ks = 0; ks < 2; ++ks)
            hfr[mt][ks] = *(const short8*)(hb + (size_t)(j0 + mt * 16 + col) * 64 + ks * 32 + quad * 8);

    const short* Tb = T + (size_t)i0 * 8192;
    int toff[2][2];
#pragma unroll
    for (int m = 0; m < 2; ++m)
#pragma unroll
        for (int ks = 0; ks < 2; ++ks)
            toff[m][ks] = ((((w * 2 + m) * 2 + ks) * 64) + lane) * 8;

    short8 ta[2][2], tb[2][2];

    auto prefetch = [&](short8 (&dst)[2][2], int i) {
        const short* Tn = Tb + (size_t)i * 8192;
#pragma unroll
        for (int m = 0; m < 2; ++m)
#pragma unroll
            for (int ks = 0; ks < 2; ++ks)
                dst[m][ks] = *(const short8*)(Tn + toff[m][ks]);
    };

    auto body2 = [&](int i, short8 (&tc)[2][2]) {
        float2v acc[4];
#pragma unroll
        for (int k = 0; k < 4; ++k) acc[k] = 0.f;
#pragma unroll
        for (int m = 0; m < 2; ++m) {
#pragma unroll
            for (int nj = 0; nj < 4; ++nj) {
                floatx4 c = {b5q[m][0], b5q[m][1], b5q[m][2], b5q[m][3]};
                c = __builtin_amdgcn_mfma_f32_16x16x32_bf16(tc[m][0], hfr[nj][0], c, 0, 0, 0);
                c = __builtin_amdgcn_mfma_f32_16x16x32_bf16(tc[m][1], hfr[nj][1], c, 0, 0, 0);
                float2v z01, z23;
                z01.x = c[0]; z01.y = c[1];
                z23.x = c[2]; z23.y = c[3];
                acc[nj] = fma2(lrelu2(z01), wq[m][0], acc[nj]);
                acc[nj] = fma2(lrelu2(z23), wq[m][1], acc[nj]);
            }
        }
        // per-i tail: quad-butterfly + single-writer plain store (no atomics)
#pragma unroll
        for (int nj = 0; nj < 4; ++nj) {
            float v = acc[nj].x + acc[nj].y;
            v += __shfl_xor(v, 16);
            v += __shfl_xor(v, 32);
            if (quad == 0) sV[w][i][nj * 16 + col] = v;
        }
    };

    prefetch(ta, 0);
    for (int ii = 0; ii < 8; ii += 2) {
        prefetch(tb, ii + 1);
        body2(ii, ta);
        if (ii + 2 < 8) prefetch(ta, ii + 2);
        body2(ii + 1, tb);
    }
    __syncthreads();

    // cross-wave sum + sigmoid + direct write (coalesced)
#pragma unroll
    for (int k = 0; k < 2; ++k) {
        int e = t + 256 * k;          // 0..511
        int il = e >> 6, jl = e & 63;
        float v = bb + sV[0][il][jl] + sV[1][il][jl] + sV[2][il][jl] + sV[3][il][jl];
        float p = 1.f / (1.f + __expf(-v));
        sP[il][jl] = p;
        int ig = i0 + il, jg = j0 + jl;
        float2v pr;
        if (!str || jg > ig) {
            pr.x = p; pr.y = 1.f - p;
            *(float2v*)(out + ((size_t)ig * NN + jg) * 2) = pr;
        } else if (jg == ig) {
            pr.x = 0.f; pr.y = 0.f;
            *(float2v*)(out + ((size_t)ig * NN + jg) * 2) = pr;
        }
    }
    __syncthreads();

    if (!str) {
        // mirror: 64 rows x 16 floats, float4 per thread
        int jr = t >> 2, f1 = (t & 3) * 4;
        float4 u;
#pragma unroll
        for (int e = 0; e < 4; ++e) {
            int ff = f1 + e;
            float p = sP[ff >> 1][jr];
            ((float*)&u)[e] = (ff & 1) ? 1.f - p : p;
        }
        *(float4*)(out + ((size_t)(j0 + jr) * NN + i0) * 2 + f1) = u;
    } else {
#pragma unroll
        for (int e = 0; e < 4; ++e) {     // mirror 64x8x2 = 1024 floats
            int f = t * 4 + e;
            int jr = f >> 4, ff = f & 15;
            int il = ff >> 1, c2 = ff & 1;
            int jg = j0 + jr, ig = i0 + il;
            if (jg > ig) {
                float p = sP[il][jr];
                out[((size_t)jg * NN + ig) * 2 + c2] = c2 ? 1.f - p : p;
            }
        }
    }
}

// ---------------------------------------------------------------------------
extern "C" void kernel_launch(void* const* d_in, const int* in_sizes, int n_in,
                              void* d_out, int out_size, void* d_ws, size_t ws_size,
                              hipStream_t stream) {
    const float* nf  = (const float*)d_in[1];   // d_in[0]=x unused (ref ignores it)
    const float* W1  = (const float*)d_in[2];
    const float* b1  = (const float*)d_in[3];
    const float* g1  = (const float*)d_in[4];
    const float* be1 = (const float*)d_in[5];
    const float* W2  = (const float*)d_in[6];
    const float* b2  = (const float*)d_in[7];
    const float* g2  = (const float*)d_in[8];
    const float* be2 = (const float*)d_in[9];
    const float* W3  = (const float*)d_in[10];
    const float* b3  = (const float*)d_in[11];
    const float* W5  = (const float*)d_in[12];
    const float* b5  = (const float*)d_in[13];
    const float* g5  = (const float*)d_in[14];
    const float* be5 = (const float*)d_in[15];
    const float* W6  = (const float*)d_in[16];
    const float* b6  = (const float*)d_in[17];
    float* out = (float*)d_out;

    float* wsf   = (float*)d_ws;
    float* stat1 = wsf;                 // 256
    float* stat2 = wsf + 256;           // 256
    float* SQe8  = wsf + 512;           // 8*256 = 2048 (per-XCD stat copies)
    float* w6d   = wsf + 2560;          // 128
    float* b6dp  = wsf + 2688;          // 1 (pad to 4096)
    short* hb    = (short*)(wsf + 4096);      // 131072 bf16
    short* Tbuf  = hb + 131072;               // 2048*8192 bf16 = 32 MB

    hipMemsetAsync(d_ws, 0, 4096 * sizeof(float), stream);

    {   // fused node pipeline (cooperative: grid.sync between BN stages)
        void* args[] = {
            (void*)&nf, (void*)&W1, (void*)&b1, (void*)&g1, (void*)&be1,
            (void*)&W2, (void*)&b2, (void*)&g2, (void*)&be2,
            (void*)&W3, (void*)&b3, (void*)&W5,
            (void*)&stat1, (void*)&stat2, (void*)&hb, (void*)&Tbuf
        };
        hipLaunchCooperativeKernel((void*)k_node, dim3(256), dim3(256),
                                   args, 0, stream);
    }

    edge_p1<<<4224, 256, 0, stream>>>(hb, Tbuf, b5, SQe8);
    k_mid<<<1, 128, 0, stream>>>(SQe8, W6, b6, g5, be5, w6d, b6dp);
    edge_p2<<<4224, 256, 0, stream>>>(hb, Tbuf, b5, w6d, b6dp, out);
}

// Round 10
// 332.781 us; speedup vs baseline: 2.9259x; 2.9259x over previous
//
#include <hip/hip_runtime.h>
#include <hip/hip_bf16.h>
#include <hip/hip_cooperative_groups.h>

namespace cg = cooperative_groups;

// ---------------------------------------------------------------------------
// ramsey_NN: node MLP (3 layers, train-mode BN) + all-pairs edge head.
// N=2048, F=64, H=128, C=2.  E = N(N-1)/2 = 2096128.
//
// R10 = R8 edge kernels + R9 k_node fusion.
// R9 post-mortem: __launch_bounds__(256,8) capped the unified reg file at 64
// regs/wave -> hfr+prefetch spilled to scratch -> 2 GB HBM spill traffic,
// 460 us/pass. (256,4) (=128-reg cap, VGPR 64, no spill) is the knee.
//   * edge_p1/p2: exact R8 bodies, __launch_bounds__(256,4).
//   * k_node: cooperative fused node pipeline (verified correct in R9).
// ---------------------------------------------------------------------------

typedef short short8 __attribute__((ext_vector_type(8)));   // 8 x bf16
typedef float floatx4 __attribute__((ext_vector_type(4)));  // MFMA C/D
typedef float float2v __attribute__((ext_vector_type(2)));  // packed f32 pair

#define NN 2048
#define EPSV 1e-5f
#define EDGEF 2096128.f

__device__ __forceinline__ float bf2f(short s) {
    return __uint_as_float(((unsigned)(unsigned short)s) << 16);
}
__device__ __forceinline__ short f2bf(float f) {   // RNE
    unsigned u = __float_as_uint(f);
    unsigned r = (u + 0x7FFFu + ((u >> 16) & 1u)) >> 16;
    return (short)r;
}
__device__ __forceinline__ float lrelu(float x) { return fmaxf(x, 0.01f * x); }
__device__ __forceinline__ float2v lrelu2(float2v z) {
    float2v r; r.x = fmaxf(z.x, 0.01f * z.x); r.y = fmaxf(z.y, 0.01f * z.y);
    return r;
}
__device__ __forceinline__ float2v fma2(float2v a, float2v b, float2v c) {
    float2v r; r.x = fmaf(a.x, b.x, c.x); r.y = fmaf(a.y, b.y, c.y); return r;
}
__device__ __forceinline__ float aload(const float* p) {   // device-coherent load
    return __hip_atomic_load(p, __ATOMIC_RELAXED, __HIP_MEMORY_SCOPE_AGENT);
}

// fragment-physical chunk index (16x16x32 bf16, A/B identity layout)
__device__ __forceinline__ int physB(int h, int f) {
    return ((((h >> 4) * 2 + (f >> 5)) * 64 + ((f >> 3) & 3) * 16 + (h & 15)) * 8) + (f & 7);
}

// 1-D active-tile decode: rows-of-8 nodes, j-tiles of 64.
// Row ig8 pinned to XCD ig8%8 (blockIdx%8 round-robin heuristic).
// Per-XCD slots: sum_{m=0}^{31}(32-m)=528; grid = 4224.
__device__ __forceinline__ void decode_tile(int bid, int& i0, int& j0, bool& str) {
    int s = bid >> 3, m = 0;
#pragma unroll 1
    while (s >= 32 - m) { s -= 32 - m; ++m; }
    i0 = ((bid & 7) + (m << 3)) * 8;
    j0 = (m + s) * 64;
    str = (s == 0);
}

// ---------------- fused node pipeline (cooperative, 256 blocks x 8 nodes) ----
__global__ __launch_bounds__(256) void k_node(
    const float* __restrict__ nf,
    const float* __restrict__ W1, const float* __restrict__ b1,
    const float* __restrict__ g1, const float* __restrict__ be1,
    const float* __restrict__ W2, const float* __restrict__ b2,
    const float* __restrict__ g2, const float* __restrict__ be2,
    const float* __restrict__ W3, const float* __restrict__ b3,
    const float* __restrict__ W5,
    float* __restrict__ stat1, float* __restrict__ stat2,
    short* __restrict__ hb, short* __restrict__ T)
{
    cg::grid_group grid = cg::this_grid();

    __shared__ float xl[8 * 64];      // nf rows (kept for residual)
    __shared__ float sA1[8 * 128];    // act1
    __shared__ float sA2[8 * 128];    // act2
    __shared__ short sW5[8192];       // W5 bf16 frag-physical
    __shared__ short sH[8 * 64];      // hb rows
    __shared__ float sS[128], sQ[128];
    __shared__ float nA[128], nB[128];

    int t = threadIdx.x, n0 = blockIdx.x * 8;

    // stage: W5 -> frag-physical bf16 (per block), nf rows, zero stats
    for (int k = 0; k < 32; ++k) {
        int idx = t + 256 * k;                 // f*128+h
        sW5[physB(idx & 127, idx >> 7)] = f2bf(W5[idx]);
    }
    xl[t] = nf[(size_t)n0 * 64 + t];
    xl[t + 256] = nf[(size_t)n0 * 64 + t + 256];
    if (t < 128) { sS[t] = 0.f; sQ[t] = 0.f; }
    __syncthreads();

    int nl = t >> 5, h0 = (t & 31) * 4;

    // ---- layer 1 ----
    {
        float acc[4];
        for (int k = 0; k < 4; ++k) acc[k] = b1[h0 + k];
        for (int f = 0; f < 64; ++f) {
            float r = xl[nl * 64 + f];
            const float* wr = W1 + f * 128 + h0;
            for (int k = 0; k < 4; ++k) acc[k] = fmaf(r, wr[k], acc[k]);
        }
        for (int k = 0; k < 4; ++k) {
            float a = lrelu(acc[k]);
            sA1[nl * 128 + h0 + k] = a;
            atomicAdd(&sS[h0 + k], a);
            atomicAdd(&sQ[h0 + k], a * a);
        }
    }
    __syncthreads();
    if (t < 128) atomicAdd(&stat1[t], sS[t]);
    else atomicAdd(&stat1[128 + (t - 128)], sQ[t - 128]);
    grid.sync();

    // ---- BN1 fold + zero stats for layer 2 ----
    if (t < 128) {
        float s = aload(stat1 + t);
        float q = aload(stat1 + 128 + t);
        float m = s * (1.f / 2048.f);
        float v = q * (1.f / 2048.f) - m * m;
        float sc = rsqrtf(v + EPSV) * g1[t];
        nA[t] = sc;
        nB[t] = be1[t] - m * sc;
        sS[t] = 0.f; sQ[t] = 0.f;
    }
    __syncthreads();
    for (int k = 0; k < 4; ++k) {
        int e = t + 256 * k;
        int h = e & 127;
        sA1[e] = sA1[e] * nA[h] + nB[h];
    }
    __syncthreads();

    // ---- layer 2 ----
    {
        float acc[4];
        for (int k = 0; k < 4; ++k) acc[k] = b2[h0 + k];
        for (int hi = 0; hi < 128; ++hi) {
            float r = sA1[nl * 128 + hi];
            const float* wr = W2 + hi * 128 + h0;
            for (int k = 0; k < 4; ++k) acc[k] = fmaf(r, wr[k], acc[k]);
        }
        for (int k = 0; k < 4; ++k) {
            float a = lrelu(acc[k]);
            sA2[nl * 128 + h0 + k] = a;
            atomicAdd(&sS[h0 + k], a);
            atomicAdd(&sQ[h0 + k], a * a);
        }
    }
    __syncthreads();
    if (t < 128) atomicAdd(&stat2[t], sS[t]);
    else atomicAdd(&stat2[128 + (t - 128)], sQ[t - 128]);
    grid.sync();

    // ---- BN2 fold ----
    if (t < 128) {
        float s = aload(stat2 + t);
        float q = aload(stat2 + 128 + t);
        float m = s * (1.f / 2048.f);
        float v = q * (1.f / 2048.f) - m * m;
        float sc = rsqrtf(v + EPSV) * g2[t];
        nA[t] = sc;
        nB[t] = be2[t] - m * sc;
    }
    __syncthreads();
    for (int k = 0; k < 4; ++k) {
        int e = t + 256 * k;
        int h = e & 127;
        sA2[e] = sA2[e] * nA[h] + nB[h];
    }
    __syncthreads();

    // ---- layer 3 + residual -> sH + hb ----
    {
        int f0 = (t & 31) * 2;
        float acc0 = 0.f, acc1 = 0.f;
        for (int hi = 0; hi < 128; ++hi) {
            float r = sA2[nl * 128 + hi];
            const float* wr = W3 + hi * 64 + f0;
            acc0 = fmaf(r, wr[0], acc0);
            acc1 = fmaf(r, wr[1], acc1);
        }
        float v0 = acc0 + b3[f0] + xl[nl * 64 + f0];
        float v1 = acc1 + b3[f0 + 1] + xl[nl * 64 + f0 + 1];
        short s0 = f2bf(v0), s1 = f2bf(v1);
        sH[nl * 64 + f0] = s0;
        sH[nl * 64 + f0 + 1] = s1;
        unsigned p = (unsigned)(unsigned short)s0 | ((unsigned)(unsigned short)s1 << 16);
        ((unsigned*)hb)[(size_t)(n0 + nl) * 32 + (f0 >> 1)] = p;
    }
    __syncthreads();

    // ---- T build: T[i] = diag(h_i) @ W5 ----
    for (int i = 0; i < 8; ++i) {
        short8* dst = (short8*)(T + (size_t)(n0 + i) * 8192);
#pragma unroll
        for (int k = 0; k < 4; ++k) {
            int c = t + 256 * k;                 // chunk 0..1023
            int ks = (c >> 6) & 1, quad = (c & 63) >> 4;
            int fb = ks * 32 + quad * 8;
            short8 wv = ((const short8*)sW5)[c];
            short8 hv = *(const short8*)(sH + i * 64 + fb);
            short8 ov;
#pragma unroll
            for (int e = 0; e < 8; ++e) ov[e] = f2bf(bf2f(wv[e]) * bf2f(hv[e]));
            dst[c] = ov;
        }
    }
}

// ---------------- BN+softmax fold (1 block) ----------------------------------
__global__ void k_mid(const float* __restrict__ SQe8, const float* __restrict__ W6,
                      const float* __restrict__ b6, const float* __restrict__ g5,
                      const float* __restrict__ be5, float* __restrict__ w6d,
                      float* __restrict__ b6d) {
    __shared__ float part[128];
    int h = threadIdx.x;
    float s = 0.f, q = 0.f;
    for (int x = 0; x < 8; ++x) {
        s += SQe8[x * 256 + h];
        q += SQe8[x * 256 + 128 + h];
    }
    float m = s / EDGEF;
    float v = q / EDGEF - m * m;
    float sc = rsqrtf(v + EPSV);
    float dW = W6[h * 2] - W6[h * 2 + 1];
    float sg = sc * g5[h];
    w6d[h] = sg * dW;
    part[h] = (be5[h] - m * sg) * dW;
    __syncthreads();
    if (h == 0) {
        float acc = b6[0] - b6[1];
        for (int k = 0; k < 128; ++k) acc += part[k];
        b6d[0] = acc;
    }
}

// ---------------- edge pass 1: BN stats (R8 config: (256,4), no spill) -------
__global__ __launch_bounds__(256, 4) void edge_p1(
    const short* __restrict__ hb, const short* __restrict__ T,
    const float* __restrict__ b5, float* __restrict__ SQe8)
{
    int i0, j0; bool str;
    decode_tile(blockIdx.x, i0, j0, str);

    int t = threadIdx.x, lane = t & 63, w = t >> 6;
    int quad = lane >> 4, col = lane & 15;

    short8 hfr[4][2];
#pragma unroll
    for (int mt = 0; mt < 4; ++mt)
#pragma unroll
        for (int ks = 0; ks < 2; ++ks)
            hfr[mt][ks] = *(const short8*)(hb + (size_t)(j0 + mt * 16 + col) * 64 + ks * 32 + quad * 8);

    const short* Tb = T + (size_t)i0 * 8192;
    int toff[2][2];
#pragma unroll
    for (int n = 0; n < 2; ++n)
#pragma unroll
        for (int ks = 0; ks < 2; ++ks)
            toff[n][ks] = ((((w * 2 + n) * 2 + ks) * 64) + lane) * 8;

    float b5c[2] = { b5[w * 32 + col], b5[w * 32 + 16 + col] };
    float2v S2[2], Q2[2];
#pragma unroll
    for (int n = 0; n < 2; ++n) { S2[n] = 0.f; Q2[n] = 0.f; }

    short8 ta[2][2], tb[2][2];

    auto prefetch = [&](short8 (&dst)[2][2], int i) {
        const short* Tn = Tb + (size_t)i * 8192;
#pragma unroll
        for (int n = 0; n < 2; ++n)
#pragma unroll
            for (int ks = 0; ks < 2; ++ks)
                dst[n][ks] = *(const short8*)(Tn + toff[n][ks]);
    };

    // clean body: no triangle masking (4160 of 4224 blocks)
    auto bodyC = [&](short8 (&tc)[2][2]) {
#pragma unroll
        for (int n = 0; n < 2; ++n) {
#pragma unroll
            for (int mt = 0; mt < 4; ++mt) {
                floatx4 c = {b5c[n], b5c[n], b5c[n], b5c[n]};
                c = __builtin_amdgcn_mfma_f32_16x16x32_bf16(hfr[mt][0], tc[n][0], c, 0, 0, 0);
                c = __builtin_amdgcn_mfma_f32_16x16x32_bf16(hfr[mt][1], tc[n][1], c, 0, 0, 0);
                float2v z01, z23;
                z01.x = c[0]; z01.y = c[1];
                z23.x = c[2]; z23.y = c[3];
                float2v a01 = lrelu2(z01), a23 = lrelu2(z23);
                S2[n] += a01 + a23;
                Q2[n] = fma2(a01, a01, Q2[n]);
                Q2[n] = fma2(a23, a23, Q2[n]);
            }
        }
    };

    // masked body: diagonal-straddling blocks only (64 of 4224)
    auto bodyM = [&](int i, short8 (&tc)[2][2]) {
        int igi = i0 + i;
#pragma unroll
        for (int n = 0; n < 2; ++n) {
#pragma unroll
            for (int mt = 0; mt < 4; ++mt) {
                floatx4 c = {b5c[n], b5c[n], b5c[n], b5c[n]};
                c = __builtin_amdgcn_mfma_f32_16x16x32_bf16(hfr[mt][0], tc[n][0], c, 0, 0, 0);
                c = __builtin_amdgcn_mfma_f32_16x16x32_bf16(hfr[mt][1], tc[n][1], c, 0, 0, 0);
                int jb = j0 + mt * 16 + quad * 4;
                float2v z01, z23;
                z01.x = (jb + 0 > igi) ? c[0] : 0.f;
                z01.y = (jb + 1 > igi) ? c[1] : 0.f;
                z23.x = (jb + 2 > igi) ? c[2] : 0.f;
                z23.y = (jb + 3 > igi) ? c[3] : 0.f;
                float2v a01 = lrelu2(z01), a23 = lrelu2(z23);
                S2[n] += a01 + a23;
                Q2[n] = fma2(a01, a01, Q2[n]);
                Q2[n] = fma2(a23, a23, Q2[n]);
            }
        }
    };

    prefetch(ta, 0);
    if (!str) {
        for (int ii = 0; ii < 8; ii += 2) {
            prefetch(tb, ii + 1);
            bodyC(ta);
            if (ii + 2 < 8) prefetch(ta, ii + 2);
            bodyC(tb);
        }
    } else {
        for (int ii = 0; ii < 8; ii += 2) {
            prefetch(tb, ii + 1);
            bodyM(ii, ta);
            if (ii + 2 < 8) prefetch(ta, ii + 2);
            bodyM(ii + 1, tb);
        }
    }

    float* dst = SQe8 + (blockIdx.x & 7) * 256;
#pragma unroll
    for (int n = 0; n < 2; ++n) {
        float Sa = S2[n].x + S2[n].y;
        float Qa = Q2[n].x + Q2[n].y;
        Sa += __shfl_xor(Sa, 16); Sa += __shfl_xor(Sa, 32);
        Qa += __shfl_xor(Qa, 16); Qa += __shfl_xor(Qa, 32);
        if (quad == 0) {
            atomicAdd(&dst[w * 32 + n * 16 + col], Sa);
            atomicAdd(&dst[128 + w * 32 + n * 16 + col], Qa);
        }
    }
}

// ---------------- edge pass 2: probabilities + symmetric write ---------------
__global__ __launch_bounds__(256, 4) void edge_p2(
    const short* __restrict__ hb, const short* __restrict__ T,
    const float* __restrict__ b5, const float* __restrict__ w6d,
    const float* __restrict__ b6dp, float* __restrict__ out)
{
    int i0, j0; bool str;
    decode_tile(blockIdx.x, i0, j0, str);
    __shared__ float sV[4][8][64];    // per-wave partial h-sums (8 KB)
    __shared__ float sP[8][65];       // probs, padded (mirror transpose)

    int t = threadIdx.x, lane = t & 63, w = t >> 6;
    int quad = lane >> 4, col = lane & 15;

    float bb = b6dp[0];
    float b5q[2][4];
    float2v wq[2][2];                 // w6d at (m, r01/r23)
#pragma unroll
    for (int m = 0; m < 2; ++m)
#pragma unroll
        for (int r = 0; r < 4; ++r) {
            int h = w * 32 + m * 16 + quad * 4 + r;
            b5q[m][r] = b5[h];
            ((float*)&wq[m][r >> 1])[r & 1] = w6d[h];
        }

    short8 hfr[4][2];
#pragma unroll
    for (int mt = 0; mt < 4; ++mt)
#pragma unroll
        for (int ks = 0; ks < 2; ++ks)
            hfr[mt][ks] = *(const short8*)(hb + (size_t)(j0 + mt * 16 + col) * 64 + ks * 32 + quad * 8);

    const short* Tb = T + (size_t)i0 * 8192;
    int toff[2][2];
#pragma unroll
    for (int m = 0; m < 2; ++m)
#pragma unroll
        for (int ks = 0; ks < 2; ++ks)
            toff[m][ks] = ((((w * 2 + m) * 2 + ks) * 64) + lane) * 8;

    short8 ta[2][2], tb[2][2];

    auto prefetch = [&](short8 (&dst)[2][2], int i) {
        const short* Tn = Tb + (size_t)i * 8192;
#pragma unroll
        for (int m = 0; m < 2; ++m)
#pragma unroll
            for (int ks = 0; ks < 2; ++ks)
                dst[m][ks] = *(const short8*)(Tn + toff[m][ks]);
    };

    auto body2 = [&](int i, short8 (&tc)[2][2]) {
        float2v acc[4];
#pragma unroll
        for (int k = 0; k < 4; ++k) acc[k] = 0.f;
#pragma unroll
        for (int m = 0; m < 2; ++m) {
#pragma unroll
            for (int nj = 0; nj < 4; ++nj) {
                floatx4 c = {b5q[m][0], b5q[m][1], b5q[m][2], b5q[m][3]};
                c = __builtin_amdgcn_mfma_f32_16x16x32_bf16(tc[m][0], hfr[nj][0], c, 0, 0, 0);
                c = __builtin_amdgcn_mfma_f32_16x16x32_bf16(tc[m][1], hfr[nj][1], c, 0, 0, 0);
                float2v z01, z23;
                z01.x = c[0]; z01.y = c[1];
                z23.x = c[2]; z23.y = c[3];
                acc[nj] = fma2(lrelu2(z01), wq[m][0], acc[nj]);
                acc[nj] = fma2(lrelu2(z23), wq[m][1], acc[nj]);
            }
        }
        // per-i tail: quad-butterfly + single-writer plain store (no atomics)
#pragma unroll
        for (int nj = 0; nj < 4; ++nj) {
            float v = acc[nj].x + acc[nj].y;
            v += __shfl_xor(v, 16);
            v += __shfl_xor(v, 32);
            if (quad == 0) sV[w][i][nj * 16 + col] = v;
        }
    };

    prefetch(ta, 0);
    for (int ii = 0; ii < 8; ii += 2) {
        prefetch(tb, ii + 1);
        body2(ii, ta);
        if (ii + 2 < 8) prefetch(ta, ii + 2);
        body2(ii + 1, tb);
    }
    __syncthreads();

    // cross-wave sum + sigmoid + direct write (coalesced)
#pragma unroll
    for (int k = 0; k < 2; ++k) {
        int e = t + 256 * k;          // 0..511
        int il = e >> 6, jl = e & 63;
        float v = bb + sV[0][il][jl] + sV[1][il][jl] + sV[2][il][jl] + sV[3][il][jl];
        float p = 1.f / (1.f + __expf(-v));
        sP[il][jl] = p;
        int ig = i0 + il, jg = j0 + jl;
        float2v pr;
        if (!str || jg > ig) {
            pr.x = p; pr.y = 1.f - p;
            *(float2v*)(out + ((size_t)ig * NN + jg) * 2) = pr;
        } else if (jg == ig) {
            pr.x = 0.f; pr.y = 0.f;
            *(float2v*)(out + ((size_t)ig * NN + jg) * 2) = pr;
        }
    }
    __syncthreads();

    if (!str) {
        // mirror: 64 rows x 16 floats, float4 per thread
        int jr = t >> 2, f1 = (t & 3) * 4;
        float4 u;
#pragma unroll
        for (int e = 0; e < 4; ++e) {
            int ff = f1 + e;
            float p = sP[ff >> 1][jr];
            ((float*)&u)[e] = (ff & 1) ? 1.f - p : p;
        }
        *(float4*)(out + ((size_t)(j0 + jr) * NN + i0) * 2 + f1) = u;
    } else {
#pragma unroll
        for (int e = 0; e < 4; ++e) {     // mirror 64x8x2 = 1024 floats
            int f = t * 4 + e;
            int jr = f >> 4, ff = f & 15;
            int il = ff >> 1, c2 = ff & 1;
            int jg = j0 + jr, ig = i0 + il;
            if (jg > ig) {
                float p = sP[il][jr];
                out[((size_t)jg * NN + ig) * 2 + c2] = c2 ? 1.f - p : p;
            }
        }
    }
}

// ---------------------------------------------------------------------------
extern "C" void kernel_launch(void* const* d_in, const int* in_sizes, int n_in,
                              void* d_out, int out_size, void* d_ws, size_t ws_size,
                              hipStream_t stream) {
    const float* nf  = (const float*)d_in[1];   // d_in[0]=x unused (ref ignores it)
    const float* W1  = (const float*)d_in[2];
    const float* b1  = (const float*)d_in[3];
    const float* g1  = (const float*)d_in[4];
    const float* be1 = (const float*)d_in[5];
    const float* W2  = (const float*)d_in[6];
    const float* b2  = (const float*)d_in[7];
    const float* g2  = (const float*)d_in[8];
    const float* be2 = (const float*)d_in[9];
    const float* W3  = (const float*)d_in[10];
    const float* b3  = (const float*)d_in[11];
    const float* W5  = (const float*)d_in[12];
    const float* b5  = (const float*)d_in[13];
    const float* g5  = (const float*)d_in[14];
    const float* be5 = (const float*)d_in[15];
    const float* W6  = (const float*)d_in[16];
    const float* b6  = (const float*)d_in[17];
    float* out = (float*)d_out;

    float* wsf   = (float*)d_ws;
    float* stat1 = wsf;                 // 256
    float* stat2 = wsf + 256;           // 256
    float* SQe8  = wsf + 512;           // 8*256 = 2048 (per-XCD stat copies)
    float* w6d   = wsf + 2560;          // 128
    float* b6dp  = wsf + 2688;          // 1 (pad to 4096)
    short* hb    = (short*)(wsf + 4096);      // 131072 bf16
    short* Tbuf  = hb + 131072;               // 2048*8192 bf16 = 32 MB

    hipMemsetAsync(d_ws, 0, 4096 * sizeof(float), stream);

    {   // fused node pipeline (cooperative: grid.sync between BN stages)
        void* args[] = {
            (void*)&nf, (void*)&W1, (void*)&b1, (void*)&g1, (void*)&be1,
            (void*)&W2, (void*)&b2, (void*)&g2, (void*)&be2,
            (void*)&W3, (void*)&b3, (void*)&W5,
            (void*)&stat1, (void*)&stat2, (void*)&hb, (void*)&Tbuf
        };
        hipLaunchCooperativeKernel((void*)k_node, dim3(256), dim3(256),
                                   args, 0, stream);
    }

    edge_p1<<<4224, 256, 0, stream>>>(hb, Tbuf, b5, SQe8);
    k_mid<<<1, 128, 0, stream>>>(SQe8, W6, b6, g5, be5, w6d, b6dp);
    edge_p2<<<4224, 256, 0, stream>>>(hb, Tbuf, b5, w6d, b6dp, out);
}